// Round 22
// baseline (145.318 us; speedup 1.0000x reference)
//
#include <hip/hip_runtime.h>
#include <math.h>

#define S_LEN 1024
#define D_DIM 64
#define NBH   16
#define RPB   14
#define NSB   74           // ceil(1024/14)

typedef unsigned short ushort_t;
typedef unsigned int uint_t;
typedef __attribute__((ext_vector_type(8))) _Float16 half8;  // 8 f16 (4 VGPRs)
typedef __attribute__((ext_vector_type(2))) _Float16 h2;
typedef __attribute__((ext_vector_type(4))) short short4v;   // 8 B
typedef __attribute__((ext_vector_type(4))) float f32x4;
typedef __attribute__((ext_vector_type(2))) float f32x2;

__device__ __forceinline__ ushort_t f16bits(float x) {
    _Float16 h = (_Float16)x;                 // RNE
    ushort_t b;
    __builtin_memcpy(&b, &h, 2);
    return b;
}
__device__ __forceinline__ h2 as_h2(uint_t u) {
    h2 r;
    __builtin_memcpy(&r, &u, 4);
    return r;
}

// ------------------------------ Prep ----------------------------------------
// blocks [0,512):    K -> f16 QK B-frag tiled layout (16B stores)
// blocks [512,768):  V transpose -> f16 PV B-frag tiled layout
// blocks [768,1024): mask bit-pack, thread-per-word
__global__ __launch_bounds__(256) void prep(
    const float* __restrict__ k, const float* __restrict__ v,
    const int* __restrict__ mask,
    ushort_t* __restrict__ kh, ushort_t* __restrict__ vh,
    unsigned* __restrict__ mw)
{
    __shared__ float Ls[64][65];
    const int tid = threadIdx.x;
    const int bx = blockIdx.x;
    if (bx < 512) {
        const int gid  = bx * 256 + tid;          // 0..131071
        const int bh   = gid >> 13;
        const int tile = (gid >> 7) & 63;
        const int ch   = (gid >> 6) & 1;
        const int lane = gid & 63;
        const int quad = lane >> 4, t15 = lane & 15;
        const float* src = k + ((size_t)bh * S_LEN + tile * 16 + t15) * D_DIM
                             + ch * 32 + quad * 8;
        float x[8];
        *(float4*)(x + 0) = *(const float4*)(src);
        *(float4*)(x + 4) = *(const float4*)(src + 4);
        ushort_t hv[8];
        #pragma unroll
        for (int i = 0; i < 8; ++i) hv[i] = f16bits(x[i]);
        *(short4v*)(kh + (size_t)gid * 8)     = *(short4v*)(hv);
        *(short4v*)(kh + (size_t)gid * 8 + 4) = *(short4v*)(hv + 4);
    } else if (bx < 768) {
        const int bi = bx - 512;
        const int tt = bi & 15, bh = bi >> 4;
        const float* vb = v + ((size_t)bh * S_LEN + tt * 64) * D_DIM;
        #pragma unroll
        for (int p = 0; p < 4; ++p) {
            int idx = p * 1024 + tid * 4;
            int r = idx >> 6, c = idx & 63;
            float4 x = *(const float4*)(vb + r * 64 + c);
            Ls[r][c] = x.x; Ls[r][c+1] = x.y; Ls[r][c+2] = x.z; Ls[r][c+3] = x.w;
        }
        __syncthreads();
        const int d = tid >> 2, c0 = (tid & 3) * 16;
        ushort_t hi[16];
        #pragma unroll
        for (int j = 0; j < 16; ++j) hi[j] = f16bits(Ls[c0 + j][d]);
        const int tb0 = tt * 8 + (c0 >> 3);
        const size_t o0 = (((size_t)bh * 128 + tb0) * 64 + d) * 8;
        const size_t o1 = (((size_t)bh * 128 + tb0 + 1) * 64 + d) * 8;
        *(short4v*)(vh + o0)     = *(short4v*)(hi);
        *(short4v*)(vh + o0 + 4) = *(short4v*)(hi + 4);
        *(short4v*)(vh + o1)     = *(short4v*)(hi + 8);
        *(short4v*)(vh + o1 + 4) = *(short4v*)(hi + 12);
    } else {
        const int gid = (bx - 768) * 256 + tid;    // 0..65535
        const int row = gid >> 5, wd = gid & 31;   // row = b*1024+s
        const int4* mp = (const int4*)(mask + (size_t)row * 1024 + wd * 32);
        unsigned bits = 0;
        #pragma unroll
        for (int p = 0; p < 8; ++p) {
            int4 qv = mp[p];
            bits |= (qv.x != 0 ? 1u : 0u) << (p * 4 + 0);
            bits |= (qv.y != 0 ? 1u : 0u) << (p * 4 + 1);
            bits |= (qv.z != 0 ? 1u : 0u) << (p * 4 + 2);
            bits |= (qv.w != 0 ? 1u : 0u) << (p * 4 + 3);
        }
        mw[(size_t)row * 32 + wd] = bits;
    }
}

// ---------- Fused (RPB=14, f16, in-place P): QK^T -> conv -> PV --------------
// grid (74 s-tiles, 16 bh), block 512 = 8 waves. LDS ~39.9 KB -> 4 blocks/CU
// (32 waves/CU; VGPR capped 64 via launch_bounds(512,8)).
// Phase A: 8 waves x 8 K-tiles; ONE 16-row f16 A-set (rows s0-1+m, x1/8).
//          dpH: col t at idx t+2, pads zeroed -> aligned b64 conv reads.
// Phase B: two passes; P held in REGISTERS (packed f16), then after a barrier
//          written IN PLACE over dpH (col t at idx t) -> no separate pP.
// Phase C: PV reads P from dpH; partials merged via small oBuf.
#define DPSTR 1040  // dp/P row stride (halfs)
__global__ __launch_bounds__(512, 8) void fused_qk_conv_av(
    const float* __restrict__ q,
    const ushort_t* __restrict__ kh, const unsigned* __restrict__ mw,
    const ushort_t* __restrict__ vh,
    const float* __restrict__ conv_w, const float* __restrict__ conv_b,
    const float* __restrict__ lin_w, const float* __restrict__ lin_b,
    float* __restrict__ out)
{
    __shared__ ushort_t dpH[16 * DPSTR];   // 33.3 KB; dp in A/B, P in C
    __shared__ float oBuf[16][68];         // 4.35 KB
    __shared__ float lsPart[16][4];        // 256 B
    __shared__ unsigned mb[16][32];        // 2 KB

    const int st = blockIdx.x, bh = blockIdx.y;
    const int s0 = st * RPB;
    const int b  = bh >> 3;
    const int tid = threadIdx.x;
    const int wave = tid >> 6, lane = tid & 63;
    const int m = lane & 15, quad = lane >> 4;

    // mask bits -> LDS (one word per thread; row o <-> s = s0-1+o)
    {
        const int o = tid >> 5, wd = tid & 31;
        const int s = s0 - 1 + o;
        mb[o][wd] = (s >= 0 && s < S_LEN)
                  ? mw[((size_t)b * S_LEN + s) * 32 + wd] : 0u;
    }
    // zero dpH pads: idx 0,1 (t=-2,-1) and 1026,1027 (t=1024,1025) per row
    if (tid < 64) {
        const int row = tid >> 2, i = tid & 3;
        const int idx = (i < 2) ? i : 1024 + i;
        dpH[row * DPSTR + idx] = 0;
    }

    // ---------------- Phase A: QK into LDS (single f16 A-set) ---------------
    const int sA = s0 - 1 + m;
    const int sQ = sA < 0 ? 0 : (sA > S_LEN - 1 ? S_LEN - 1 : sA);
    const float* qp = q + ((size_t)bh * S_LEN + sQ) * D_DIM + quad * 8;
    float qa[16];
    *(float4*)(qa + 0)  = *(const float4*)(qp + 0);
    *(float4*)(qa + 4)  = *(const float4*)(qp + 4);
    *(float4*)(qa + 8)  = *(const float4*)(qp + 32);
    *(float4*)(qa + 12) = *(const float4*)(qp + 36);
    half8 AH0, AH1;
    #pragma unroll
    for (int i = 0; i < 8; ++i) {
        AH0[i] = (_Float16)(qa[i] * 0.125f);
        AH1[i] = (_Float16)(qa[8 + i] * 0.125f);
    }

    #pragma unroll
    for (int tt = 0; tt < 8; ++tt) {
        const int tile = wave * 8 + tt;
        const size_t kb = (((size_t)bh * 64 + tile) * 128 + lane) * 8;
        half8 KH0 = *(const half8*)(kh + kb);
        half8 KH1 = *(const half8*)(kh + kb + 512);
        f32x4 a = {0.f, 0.f, 0.f, 0.f};
        a = __builtin_amdgcn_mfma_f32_16x16x32_f16(AH0, KH0, a, 0, 0, 0);
        a = __builtin_amdgcn_mfma_f32_16x16x32_f16(AH1, KH1, a, 0, 0, 0);
        const int col = tile * 16 + m;
        #pragma unroll
        for (int r = 0; r < 4; ++r) {
            const int row = quad * 4 + r;
            const int s = s0 - 1 + row;
            const float v = (s >= 0 && s < S_LEN) ? a[r] : 0.f;
            dpH[row * DPSTR + col + 2] = f16bits(v);
        }
    }

    float w[36];
    #pragma unroll
    for (int i = 0; i < 36; ++i) w[i] = conv_w[i];
    float cb[4], lw[4];
    #pragma unroll
    for (int f = 0; f < 4; ++f) { cb[f] = conv_b[f]; lw[f] = lin_w[f]; }
    const float lb = lin_b[0];
    const f32x2 zero2 = {0.f, 0.f};
    const f32x2 c001  = {0.01f, 0.01f};

    __syncthreads();

    // ---------------- Phase B: conv + mask + exp (P held in registers) ------
    const int rh = tid >> 8, cg = tid & 255, c0 = cg * 4;
    uint2 Ps[8];           // packed f16 P: [pass*4 + jo]
    #pragma unroll
    for (int pass = 0; pass < 2; ++pass) {
        const int obase = rh * 8 + pass * 4;        // first of 4 output rows
        float rowv[6][6];
        #pragma unroll
        for (int jj = 0; jj < 6; ++jj) {
            const int dr = obase - 1 + jj;          // -1..16
            if (dr >= 0 && dr < 16) {
                const ushort_t* rp = &dpH[dr * DPSTR + c0];
                uint2 r0 = *(const uint2*)rp;        // t: c0-2,c0-1 | c0,c0+1
                uint2 r1 = *(const uint2*)(rp + 4);  // t: c0+2,c0+3 | c0+4,c0+5
                h2 pA = as_h2(r0.x), pB = as_h2(r0.y);
                h2 pC = as_h2(r1.x), pD = as_h2(r1.y);
                rowv[jj][0] = (float)pA[1];
                rowv[jj][1] = (float)pB[0]; rowv[jj][2] = (float)pB[1];
                rowv[jj][3] = (float)pC[0]; rowv[jj][4] = (float)pC[1];
                rowv[jj][5] = (float)pD[0];
            } else {
                #pragma unroll
                for (int i = 0; i < 6; ++i) rowv[jj][i] = 0.f;
            }
        }
        float ls[4];
        #pragma unroll
        for (int jo = 0; jo < 4; ++jo) {
            const int o = obase + jo;
            const bool act = (o >= 1) && (o <= RPB) && (s0 - 1 + o < S_LEN);
            if (act) {
                f32x2 pa = {lb, lb}, pb = {lb, lb};
                #pragma unroll
                for (int f = 0; f < 4; ++f) {
                    f32x2 ca = {cb[f], cb[f]}, cbv = ca;
                    #pragma unroll
                    for (int dr = 0; dr < 3; ++dr) {
                        const float* vv = rowv[jo + dr];
                        #pragma unroll
                        for (int dc = 0; dc < 3; ++dc) {
                            const float wt = w[f * 9 + dr * 3 + dc];
                            const f32x2 wt2 = {wt, wt};
                            f32x2 ia = {vv[dc],     vv[dc + 1]};
                            f32x2 ib = {vv[dc + 2], vv[dc + 3]};
                            ca  = __builtin_elementwise_fma(wt2, ia, ca);
                            cbv = __builtin_elementwise_fma(wt2, ib, cbv);
                        }
                    }
                    const f32x2 lwv = {lw[f], lw[f]};
                    f32x2 la  = __builtin_elementwise_fma(
                        c001, __builtin_elementwise_min(ca, zero2),
                        __builtin_elementwise_max(ca, zero2));
                    f32x2 lb2 = __builtin_elementwise_fma(
                        c001, __builtin_elementwise_min(cbv, zero2),
                        __builtin_elementwise_max(cbv, zero2));
                    pa = __builtin_elementwise_fma(lwv, la, pa);
                    pb = __builtin_elementwise_fma(lwv, lb2, pb);
                }
                const unsigned word = mb[o][cg >> 3];
                const unsigned nib  = (word >> ((cg & 7) * 4)) & 0xFu;
                float pre[4] = {pa.x, pa.y, pb.x, pb.y};
                #pragma unroll
                for (int i = 0; i < 4; ++i)
                    if (!((nib >> i) & 1u)) pre[i] = -1e30f;
                float pv[4];
                #pragma unroll
                for (int i = 0; i < 4; ++i) pv[i] = __expf(pre[i]);
                ls[jo] = (pv[0] + pv[1]) + (pv[2] + pv[3]);
                Ps[pass * 4 + jo].x =
                    (uint_t)f16bits(pv[0]) | ((uint_t)f16bits(pv[1]) << 16);
                Ps[pass * 4 + jo].y =
                    (uint_t)f16bits(pv[2]) | ((uint_t)f16bits(pv[3]) << 16);
            } else {
                Ps[pass * 4 + jo].x = 0u;
                Ps[pass * 4 + jo].y = 0u;
                ls[jo] = 0.f;
            }
        }
        #pragma unroll
        for (int jo = 0; jo < 4; ++jo) {
            float t = ls[jo];
            #pragma unroll
            for (int off = 1; off < 64; off <<= 1) t += __shfl_xor(t, off);
            if (lane == 0) lsPart[obase + jo][wave & 3] = t;
        }
    }
    __syncthreads();   // all dp reads done -> safe to overwrite dpH with P

    // write P in place over dpH (col t at idx t)
    #pragma unroll
    for (int i = 0; i < 8; ++i) {
        const int o = rh * 8 + i;       // (pass*4+jo) -> row order 0..7 per rh
        *(uint2*)&dpH[o * DPSTR + c0] = Ps[i];
    }
    __syncthreads();

    // ---------------- Phase C: PV (reads P from dpH) ------------------------
    const int d0 = (wave & 3) * 16;
    const int th = wave >> 2;
    f32x4 O = {0.f, 0.f, 0.f, 0.f};
    #pragma unroll 4
    for (int i = 0; i < 16; ++i) {
        const int c = th * 16 + i;
        half8 ph = *(const half8*)&dpH[m * DPSTR + c * 32 + quad * 8];
        const size_t vb = (((size_t)bh * 128 + c * 4 + quad) * 64 + d0 + m) * 8;
        half8 vv = *(const half8*)(vh + vb);
        O = __builtin_amdgcn_mfma_f32_16x16x32_f16(ph, vv, O, 0, 0, 0);
    }
    if (wave < 4) {
        #pragma unroll
        for (int r = 0; r < 4; ++r) oBuf[quad * 4 + r][d0 + m] = O[r];
    }
    __syncthreads();
    if (wave >= 4) {
        #pragma unroll
        for (int r = 0; r < 4; ++r) {
            const int br = quad * 4 + r;
            const int s = s0 - 1 + br;
            if (br >= 1 && br <= RPB && s < S_LEN) {
                const float lsum = (lsPart[br][0] + lsPart[br][1]) +
                                   (lsPart[br][2] + lsPart[br][3]);
                out[((size_t)bh * S_LEN + s) * D_DIM + d0 + m] =
                    (O[r] + oBuf[br][d0 + m]) / lsum;
            }
        }
    }
}

extern "C" void kernel_launch(void* const* d_in, const int* in_sizes, int n_in,
                              void* d_out, int out_size, void* d_ws, size_t ws_size,
                              hipStream_t stream) {
    const float* q      = (const float*)d_in[0];
    const float* k      = (const float*)d_in[1];
    const float* v      = (const float*)d_in[2];
    const int*   mask   = (const int*)d_in[3];
    const float* conv_w = (const float*)d_in[4];
    const float* conv_b = (const float*)d_in[5];
    const float* lin_w  = (const float*)d_in[6];
    const float* lin_b  = (const float*)d_in[7];
    float* out = (float*)d_out;

    char* wsb = (char*)d_ws;
    const size_t MB = 1024 * 1024;
    ushort_t* kh = (ushort_t*)(wsb + 0 * MB);     // 2 MiB
    ushort_t* vh = (ushort_t*)(wsb + 2 * MB);     // 2 MiB
    unsigned* mw = (unsigned*)(wsb + 4 * MB);     // 256 KiB

    prep<<<dim3(1024), 256, 0, stream>>>(k, v, mask, kh, vh, mw);
    fused_qk_conv_av<<<dim3(NSB, NBH), 512, 0, stream>>>(
        q, kh, mw, vh, conv_w, conv_b, lin_w, lin_b, out);
}

// Round 23
// 120.875 us; speedup vs baseline: 1.2022x; 1.2022x over previous
//
#include <hip/hip_runtime.h>
#include <math.h>

#define S_LEN 1024
#define D_DIM 64
#define NBH   16
#define RPB   14
#define NSB   74           // ceil(1024/14)

typedef unsigned short ushort_t;
typedef unsigned int uint_t;
typedef __attribute__((ext_vector_type(8))) _Float16 half8;  // 8 f16 (4 VGPRs)
typedef __attribute__((ext_vector_type(2))) _Float16 h2;
typedef __attribute__((ext_vector_type(4))) short short4v;   // 8 B
typedef __attribute__((ext_vector_type(4))) float f32x4;
typedef __attribute__((ext_vector_type(2))) float f32x2;

__device__ __forceinline__ ushort_t f16bits(float x) {
    _Float16 h = (_Float16)x;                 // RNE
    ushort_t b;
    __builtin_memcpy(&b, &h, 2);
    return b;
}
__device__ __forceinline__ h2 as_h2(uint_t u) {
    h2 r;
    __builtin_memcpy(&r, &u, 4);
    return r;
}

// ------------------------------ Prep ----------------------------------------
// blocks [0,512):    K -> f16 QK B-frag tiled layout (16B stores)
// blocks [512,768):  V transpose -> f16 PV B-frag tiled layout
// blocks [768,1024): mask bit-pack, thread-per-word
__global__ __launch_bounds__(256) void prep(
    const float* __restrict__ k, const float* __restrict__ v,
    const int* __restrict__ mask,
    ushort_t* __restrict__ kh, ushort_t* __restrict__ vh,
    unsigned* __restrict__ mw)
{
    __shared__ float Ls[64][65];
    const int tid = threadIdx.x;
    const int bx = blockIdx.x;
    if (bx < 512) {
        const int gid  = bx * 256 + tid;          // 0..131071
        const int bh   = gid >> 13;
        const int tile = (gid >> 7) & 63;
        const int ch   = (gid >> 6) & 1;
        const int lane = gid & 63;
        const int quad = lane >> 4, t15 = lane & 15;
        const float* src = k + ((size_t)bh * S_LEN + tile * 16 + t15) * D_DIM
                             + ch * 32 + quad * 8;
        float x[8];
        *(float4*)(x + 0) = *(const float4*)(src);
        *(float4*)(x + 4) = *(const float4*)(src + 4);
        ushort_t hv[8];
        #pragma unroll
        for (int i = 0; i < 8; ++i) hv[i] = f16bits(x[i]);
        *(short4v*)(kh + (size_t)gid * 8)     = *(short4v*)(hv);
        *(short4v*)(kh + (size_t)gid * 8 + 4) = *(short4v*)(hv + 4);
    } else if (bx < 768) {
        const int bi = bx - 512;
        const int tt = bi & 15, bh = bi >> 4;
        const float* vb = v + ((size_t)bh * S_LEN + tt * 64) * D_DIM;
        #pragma unroll
        for (int p = 0; p < 4; ++p) {
            int idx = p * 1024 + tid * 4;
            int r = idx >> 6, c = idx & 63;
            float4 x = *(const float4*)(vb + r * 64 + c);
            Ls[r][c] = x.x; Ls[r][c+1] = x.y; Ls[r][c+2] = x.z; Ls[r][c+3] = x.w;
        }
        __syncthreads();
        const int d = tid >> 2, c0 = (tid & 3) * 16;
        ushort_t hi[16];
        #pragma unroll
        for (int j = 0; j < 16; ++j) hi[j] = f16bits(Ls[c0 + j][d]);
        const int tb0 = tt * 8 + (c0 >> 3);
        const size_t o0 = (((size_t)bh * 128 + tb0) * 64 + d) * 8;
        const size_t o1 = (((size_t)bh * 128 + tb0 + 1) * 64 + d) * 8;
        *(short4v*)(vh + o0)     = *(short4v*)(hi);
        *(short4v*)(vh + o0 + 4) = *(short4v*)(hi + 4);
        *(short4v*)(vh + o1)     = *(short4v*)(hi + 8);
        *(short4v*)(vh + o1 + 4) = *(short4v*)(hi + 12);
    } else {
        const int gid = (bx - 768) * 256 + tid;    // 0..65535
        const int row = gid >> 5, wd = gid & 31;   // row = b*1024+s
        const int4* mp = (const int4*)(mask + (size_t)row * 1024 + wd * 32);
        unsigned bits = 0;
        #pragma unroll
        for (int p = 0; p < 8; ++p) {
            int4 qv = mp[p];
            bits |= (qv.x != 0 ? 1u : 0u) << (p * 4 + 0);
            bits |= (qv.y != 0 ? 1u : 0u) << (p * 4 + 1);
            bits |= (qv.z != 0 ? 1u : 0u) << (p * 4 + 2);
            bits |= (qv.w != 0 ? 1u : 0u) << (p * 4 + 3);
        }
        mw[(size_t)row * 32 + wd] = bits;
    }
}

// ---------- Fused (RPB=14, f16, in-place P): QK^T -> conv -> PV --------------
// grid (74 s-tiles, 16 bh), block 512 = 8 waves. LDS ~39.9 KB.
// NO waves-per-EU cap: natural VGPR (~60) -> 3-4 blocks/CU without spill.
// Phase A: 8 waves x 8 K-tiles; ONE 16-row f16 A-set (rows s0-1+m, x1/8).
//          dpH: col t at idx t+2, pads zeroed -> aligned b64 conv reads.
// Phase B: two passes; P held in REGISTERS (packed f16), then after a barrier
//          written IN PLACE over dpH (col t at idx t) -> no separate pP.
// Phase C: PV reads P from dpH; partials merged via small oBuf.
#define DPSTR 1040  // dp/P row stride (halfs)
__global__ __launch_bounds__(512) void fused_qk_conv_av(
    const float* __restrict__ q,
    const ushort_t* __restrict__ kh, const unsigned* __restrict__ mw,
    const ushort_t* __restrict__ vh,
    const float* __restrict__ conv_w, const float* __restrict__ conv_b,
    const float* __restrict__ lin_w, const float* __restrict__ lin_b,
    float* __restrict__ out)
{
    __shared__ ushort_t dpH[16 * DPSTR];   // 33.3 KB; dp in A/B, P in C
    __shared__ float oBuf[16][68];         // 4.35 KB
    __shared__ float lsPart[16][4];        // 256 B
    __shared__ unsigned mb[16][32];        // 2 KB

    const int st = blockIdx.x, bh = blockIdx.y;
    const int s0 = st * RPB;
    const int b  = bh >> 3;
    const int tid = threadIdx.x;
    const int wave = tid >> 6, lane = tid & 63;
    const int m = lane & 15, quad = lane >> 4;

    // mask bits -> LDS (one word per thread; row o <-> s = s0-1+o)
    {
        const int o = tid >> 5, wd = tid & 31;
        const int s = s0 - 1 + o;
        mb[o][wd] = (s >= 0 && s < S_LEN)
                  ? mw[((size_t)b * S_LEN + s) * 32 + wd] : 0u;
    }
    // zero dpH pads: idx 0,1 (t=-2,-1) and 1026,1027 (t=1024,1025) per row
    if (tid < 64) {
        const int row = tid >> 2, i = tid & 3;
        const int idx = (i < 2) ? i : 1024 + i;
        dpH[row * DPSTR + idx] = 0;
    }

    // ---------------- Phase A: QK into LDS (single f16 A-set) ---------------
    const int sA = s0 - 1 + m;
    const int sQ = sA < 0 ? 0 : (sA > S_LEN - 1 ? S_LEN - 1 : sA);
    const float* qp = q + ((size_t)bh * S_LEN + sQ) * D_DIM + quad * 8;
    float qa[16];
    *(float4*)(qa + 0)  = *(const float4*)(qp + 0);
    *(float4*)(qa + 4)  = *(const float4*)(qp + 4);
    *(float4*)(qa + 8)  = *(const float4*)(qp + 32);
    *(float4*)(qa + 12) = *(const float4*)(qp + 36);
    half8 AH0, AH1;
    #pragma unroll
    for (int i = 0; i < 8; ++i) {
        AH0[i] = (_Float16)(qa[i] * 0.125f);
        AH1[i] = (_Float16)(qa[8 + i] * 0.125f);
    }

    #pragma unroll
    for (int tt = 0; tt < 8; ++tt) {
        const int tile = wave * 8 + tt;
        const size_t kb = (((size_t)bh * 64 + tile) * 128 + lane) * 8;
        half8 KH0 = *(const half8*)(kh + kb);
        half8 KH1 = *(const half8*)(kh + kb + 512);
        f32x4 a = {0.f, 0.f, 0.f, 0.f};
        a = __builtin_amdgcn_mfma_f32_16x16x32_f16(AH0, KH0, a, 0, 0, 0);
        a = __builtin_amdgcn_mfma_f32_16x16x32_f16(AH1, KH1, a, 0, 0, 0);
        const int col = tile * 16 + m;
        #pragma unroll
        for (int r = 0; r < 4; ++r) {
            const int row = quad * 4 + r;
            const int s = s0 - 1 + row;
            const float v = (s >= 0 && s < S_LEN) ? a[r] : 0.f;
            dpH[row * DPSTR + col + 2] = f16bits(v);
        }
    }

    float w[36];
    #pragma unroll
    for (int i = 0; i < 36; ++i) w[i] = conv_w[i];
    float cb[4], lw[4];
    #pragma unroll
    for (int f = 0; f < 4; ++f) { cb[f] = conv_b[f]; lw[f] = lin_w[f]; }
    const float lb = lin_b[0];
    const f32x2 zero2 = {0.f, 0.f};
    const f32x2 c001  = {0.01f, 0.01f};

    __syncthreads();

    // ---------------- Phase B: conv + mask + exp (P held in registers) ------
    const int rh = tid >> 8, cg = tid & 255, c0 = cg * 4;
    uint2 Ps[8];           // packed f16 P: [pass*4 + jo]
    #pragma unroll
    for (int pass = 0; pass < 2; ++pass) {
        const int obase = rh * 8 + pass * 4;        // first of 4 output rows
        float rowv[6][6];
        #pragma unroll
        for (int jj = 0; jj < 6; ++jj) {
            const int dr = obase - 1 + jj;          // -1..16
            if (dr >= 0 && dr < 16) {
                const ushort_t* rp = &dpH[dr * DPSTR + c0];
                uint2 r0 = *(const uint2*)rp;        // t: c0-2,c0-1 | c0,c0+1
                uint2 r1 = *(const uint2*)(rp + 4);  // t: c0+2,c0+3 | c0+4,c0+5
                h2 pA = as_h2(r0.x), pB = as_h2(r0.y);
                h2 pC = as_h2(r1.x), pD = as_h2(r1.y);
                rowv[jj][0] = (float)pA[1];
                rowv[jj][1] = (float)pB[0]; rowv[jj][2] = (float)pB[1];
                rowv[jj][3] = (float)pC[0]; rowv[jj][4] = (float)pC[1];
                rowv[jj][5] = (float)pD[0];
            } else {
                #pragma unroll
                for (int i = 0; i < 6; ++i) rowv[jj][i] = 0.f;
            }
        }
        float ls[4];
        #pragma unroll
        for (int jo = 0; jo < 4; ++jo) {
            const int o = obase + jo;
            const bool act = (o >= 1) && (o <= RPB) && (s0 - 1 + o < S_LEN);
            if (act) {
                f32x2 pa = {lb, lb}, pb = {lb, lb};
                #pragma unroll
                for (int f = 0; f < 4; ++f) {
                    f32x2 ca = {cb[f], cb[f]}, cbv = ca;
                    #pragma unroll
                    for (int dr = 0; dr < 3; ++dr) {
                        const float* vv = rowv[jo + dr];
                        #pragma unroll
                        for (int dc = 0; dc < 3; ++dc) {
                            const float wt = w[f * 9 + dr * 3 + dc];
                            const f32x2 wt2 = {wt, wt};
                            f32x2 ia = {vv[dc],     vv[dc + 1]};
                            f32x2 ib = {vv[dc + 2], vv[dc + 3]};
                            ca  = __builtin_elementwise_fma(wt2, ia, ca);
                            cbv = __builtin_elementwise_fma(wt2, ib, cbv);
                        }
                    }
                    const f32x2 lwv = {lw[f], lw[f]};
                    f32x2 la  = __builtin_elementwise_fma(
                        c001, __builtin_elementwise_min(ca, zero2),
                        __builtin_elementwise_max(ca, zero2));
                    f32x2 lb2 = __builtin_elementwise_fma(
                        c001, __builtin_elementwise_min(cbv, zero2),
                        __builtin_elementwise_max(cbv, zero2));
                    pa = __builtin_elementwise_fma(lwv, la, pa);
                    pb = __builtin_elementwise_fma(lwv, lb2, pb);
                }
                const unsigned word = mb[o][cg >> 3];
                const unsigned nib  = (word >> ((cg & 7) * 4)) & 0xFu;
                float pre[4] = {pa.x, pa.y, pb.x, pb.y};
                #pragma unroll
                for (int i = 0; i < 4; ++i)
                    if (!((nib >> i) & 1u)) pre[i] = -1e30f;
                float pv[4];
                #pragma unroll
                for (int i = 0; i < 4; ++i) pv[i] = __expf(pre[i]);
                ls[jo] = (pv[0] + pv[1]) + (pv[2] + pv[3]);
                Ps[pass * 4 + jo].x =
                    (uint_t)f16bits(pv[0]) | ((uint_t)f16bits(pv[1]) << 16);
                Ps[pass * 4 + jo].y =
                    (uint_t)f16bits(pv[2]) | ((uint_t)f16bits(pv[3]) << 16);
            } else {
                Ps[pass * 4 + jo].x = 0u;
                Ps[pass * 4 + jo].y = 0u;
                ls[jo] = 0.f;
            }
        }
        #pragma unroll
        for (int jo = 0; jo < 4; ++jo) {
            float t = ls[jo];
            #pragma unroll
            for (int off = 1; off < 64; off <<= 1) t += __shfl_xor(t, off);
            if (lane == 0) lsPart[obase + jo][wave & 3] = t;
        }
    }
    __syncthreads();   // all dp reads done -> safe to overwrite dpH with P

    // write P in place over dpH (col t at idx t)
    #pragma unroll
    for (int i = 0; i < 8; ++i) {
        const int o = rh * 8 + i;
        *(uint2*)&dpH[o * DPSTR + c0] = Ps[i];
    }
    __syncthreads();

    // ---------------- Phase C: PV (reads P from dpH) ------------------------
    const int d0 = (wave & 3) * 16;
    const int th = wave >> 2;
    f32x4 O = {0.f, 0.f, 0.f, 0.f};
    #pragma unroll 4
    for (int i = 0; i < 16; ++i) {
        const int c = th * 16 + i;
        half8 ph = *(const half8*)&dpH[m * DPSTR + c * 32 + quad * 8];
        const size_t vb = (((size_t)bh * 128 + c * 4 + quad) * 64 + d0 + m) * 8;
        half8 vv = *(const half8*)(vh + vb);
        O = __builtin_amdgcn_mfma_f32_16x16x32_f16(ph, vv, O, 0, 0, 0);
    }
    if (wave < 4) {
        #pragma unroll
        for (int r = 0; r < 4; ++r) oBuf[quad * 4 + r][d0 + m] = O[r];
    }
    __syncthreads();
    if (wave >= 4) {
        #pragma unroll
        for (int r = 0; r < 4; ++r) {
            const int br = quad * 4 + r;
            const int s = s0 - 1 + br;
            if (br >= 1 && br <= RPB && s < S_LEN) {
                const float lsum = (lsPart[br][0] + lsPart[br][1]) +
                                   (lsPart[br][2] + lsPart[br][3]);
                out[((size_t)bh * S_LEN + s) * D_DIM + d0 + m] =
                    (O[r] + oBuf[br][d0 + m]) / lsum;
            }
        }
    }
}

extern "C" void kernel_launch(void* const* d_in, const int* in_sizes, int n_in,
                              void* d_out, int out_size, void* d_ws, size_t ws_size,
                              hipStream_t stream) {
    const float* q      = (const float*)d_in[0];
    const float* k      = (const float*)d_in[1];
    const float* v      = (const float*)d_in[2];
    const int*   mask   = (const int*)d_in[3];
    const float* conv_w = (const float*)d_in[4];
    const float* conv_b = (const float*)d_in[5];
    const float* lin_w  = (const float*)d_in[6];
    const float* lin_b  = (const float*)d_in[7];
    float* out = (float*)d_out;

    char* wsb = (char*)d_ws;
    const size_t MB = 1024 * 1024;
    ushort_t* kh = (ushort_t*)(wsb + 0 * MB);     // 2 MiB
    ushort_t* vh = (ushort_t*)(wsb + 2 * MB);     // 2 MiB
    unsigned* mw = (unsigned*)(wsb + 4 * MB);     // 256 KiB

    prep<<<dim3(1024), 256, 0, stream>>>(k, v, mask, kh, vh, mw);
    fused_qk_conv_av<<<dim3(NSB, NBH), 512, 0, stream>>>(
        q, kh, mw, vh, conv_w, conv_b, lin_w, lin_b, out);
}